// Round 5
// baseline (136.578 us; speedup 1.0000x reference)
//
#include <hip/hip_runtime.h>

// GraphProjection, round 8: f4 fully staged in LDS; block = 400 points.
//
// Evidence: r3/r4/r6/r7 (wildly different structures) all plateau at
// ~22-24 TB/s of combined L2 traffic (1.54 GB gather reads + 385 MB writes
// = 1.925 GB -> ~80-90us).  Issue/latency models predict 10-20us.  So the
// family is L2-traffic-bound; the only lever is moving fewer bytes.
//
// f4 = 53% of gather bytes (512/960 channels) and is only 100KB -> fits in
// LDS.  Stage it once per block (1024 thr, 400 points) and serve f4 gathers
// from the LDS pipe (separate per-CU resource, lane-consecutive =
// conflict-free).  L2 traffic: 1.925 GB -> ~1.13 GB.
//   * wave = point (r7 mapping): weights/corner offsets wave-uniform,
//     SGPR-base loads, lane-consecutive scalar stores (coalesced at any
//     offset).
//   * NT stores (no-allocate): keep the 1.5MB feature maps resident in L2
//     instead of letting 385MB of write data evict them (r3-NT=80 vs
//     r7-regular=88).  Scalar NT has no partial-line hazard: each row is
//     written as one contiguous span.
//   * grid = ceil(N/400) = 250 blocks = 1 block/CU (100KB LDS), 16 waves/CU.

#define ROWF    963    // 3 coords + 960 samples
#define PPB     400    // points per block
#define THREADS 1024
#define F4SZ    (7 * 7 * 512)

typedef float fx4 __attribute__((ext_vector_type(4)));

template<int H, int C, int CHBASE>
__device__ __forceinline__ void do_level_global(
    const float* __restrict__ f, float h, float w,
    float* __restrict__ orow, int lane)
{
    const float scale = (float)H / 224.0f;   // exact power-of-2 ratio
    const float x = h * scale, y = w * scale;
    const float x1f = floorf(x), x2f = fminf(ceilf(x), (float)(H - 1));
    const float y1f = floorf(y), y2f = fminf(ceilf(y), (float)(H - 1));
    const int xi1 = (int)x1f, xi2 = (int)x2f;
    const int yi1 = (int)y1f, yi2 = (int)y2f;

    const float w11 = (x2f - x) * (y2f - y);
    const float w21 = (x - x1f) * (y2f - y);
    const float w12 = (x2f - x) * (y - y1f);
    const float w22 = (x - x1f) * (y - y1f);

    // wave-uniform corner offsets -> SGPR; loads = SGPR base + lane voffset
    const float* q11 = f + __builtin_amdgcn_readfirstlane((xi1 * H + yi1) * C);
    const float* q21 = f + __builtin_amdgcn_readfirstlane((xi2 * H + yi1) * C);
    const float* q12 = f + __builtin_amdgcn_readfirstlane((xi1 * H + yi2) * C);
    const float* q22 = f + __builtin_amdgcn_readfirstlane((xi2 * H + yi2) * C);

    #pragma unroll
    for (int k = 0; k < C / 64; ++k) {
        const int c = lane + 64 * k;
        const float v = w11 * q11[c] + w21 * q21[c]
                      + w12 * q12[c] + w22 * q22[c];
        __builtin_nontemporal_store(v, &orow[CHBASE + c]);
    }
}

__global__ __launch_bounds__(THREADS) void graphproj_kernel(
    const float* __restrict__ coords,
    const float* __restrict__ f1, const float* __restrict__ f2,
    const float* __restrict__ f3, const float* __restrict__ f4,
    float* __restrict__ out, int N)
{
    __shared__ float s_f4[F4SZ];   // 100352 B

    const int tid = threadIdx.x;

    // ---- stage f4 entirely into LDS (coalesced fx4) ----
    {
        const fx4* __restrict__ src = (const fx4*)f4;
        fx4* dst = (fx4*)s_f4;
        #pragma unroll 1
        for (int i = tid; i < F4SZ / 4; i += THREADS) dst[i] = src[i];
    }
    __syncthreads();

    const int lane  = tid & 63;
    const int wid   = __builtin_amdgcn_readfirstlane(tid >> 6);
    const int pbase = blockIdx.x * PPB;

    #pragma unroll 1
    for (int j = 0; j < PPB / 16; ++j) {
        const int p = pbase + wid + j * 16;   // wave-uniform, monotone in j
        if (p >= N) break;

        const float X = coords[p * 3 + 0];
        const float Y = coords[p * 3 + 1];
        const float Z = coords[p * 3 + 2];

        float h = 250.0f * (-Y) / (-Z) + 112.0f;
        float w = 250.0f * X / (-Z) + 112.0f;
        h = fminf(fmaxf(h, 0.0f), 223.0f);
        w = fminf(fmaxf(w, 0.0f), 223.0f);

        float* orow = out + (size_t)p * ROWF + 3;

        if (lane < 3) {
            out[(size_t)p * ROWF + lane] = (lane == 0) ? X : (lane == 1) ? Y : Z;
        }

        do_level_global<56,  64,   0>(f1, h, w, orow, lane);
        do_level_global<28, 128,  64>(f2, h, w, orow, lane);
        do_level_global<14, 256, 192>(f3, h, w, orow, lane);

        // ---- f4 from LDS ----
        {
            const float scale = 7.0f / 224.0f;
            const float x = h * scale, y = w * scale;
            const float x1f = floorf(x), x2f = fminf(ceilf(x), 6.0f);
            const float y1f = floorf(y), y2f = fminf(ceilf(y), 6.0f);
            const int xi1 = (int)x1f, xi2 = (int)x2f;
            const int yi1 = (int)y1f, yi2 = (int)y2f;

            const float w11 = (x2f - x) * (y2f - y);
            const float w21 = (x - x1f) * (y2f - y);
            const float w12 = (x2f - x) * (y - y1f);
            const float w22 = (x - x1f) * (y - y1f);

            const int o11 = (xi1 * 7 + yi1) * 512;
            const int o21 = (xi2 * 7 + yi1) * 512;
            const int o12 = (xi1 * 7 + yi2) * 512;
            const int o22 = (xi2 * 7 + yi2) * 512;

            #pragma unroll
            for (int k = 0; k < 8; ++k) {
                const int c = lane + 64 * k;
                const float v = w11 * s_f4[o11 + c] + w21 * s_f4[o21 + c]
                              + w12 * s_f4[o12 + c] + w22 * s_f4[o22 + c];
                __builtin_nontemporal_store(v, &orow[448 + c]);
            }
        }
    }
}

extern "C" void kernel_launch(void* const* d_in, const int* in_sizes, int n_in,
                              void* d_out, int out_size, void* d_ws, size_t ws_size,
                              hipStream_t stream) {
    const float* coords = (const float*)d_in[0];
    const float* f1 = (const float*)d_in[1];
    const float* f2 = (const float*)d_in[2];
    const float* f3 = (const float*)d_in[3];
    const float* f4 = (const float*)d_in[4];
    float* out = (float*)d_out;
    const int N = in_sizes[0] / 3;

    const int blocks = (N + PPB - 1) / PPB;
    graphproj_kernel<<<blocks, THREADS, 0, stream>>>(coords, f1, f2, f3, f4, out, N);
}

// Round 6
// 80.228 us; speedup vs baseline: 1.7024x; 1.7024x over previous
//
#include <hip/hip_runtime.h>

// GraphProjection, FINAL (revert to round-0 champion, 76.9-80.0 us).
//
// Session conclusion: this kernel sits at the measured mixed read+write
// L2/fabric ceiling (~22-24 TB/s combined, 1.92 GB of traffic -> ~80 us):
//   * reads are intrinsic: bilinear = 4 corners x 960 ch x 4 B x 100K pts
//     = 1.536 GB, no reuse (random points), and LDS cannot serve b32-grain
//     gathers faster than L2 serves dwordx4 (44 B/cyc/CU vs ~56+).
//   * writes fixed: 385 MB; pure-write fill kernel itself only reaches
//     6.9-7.0 TB/s.
//   * removing the LDS bank conflicts (r6 swizzle) or LDS entirely (r7
//     wave-uniform) made it SLOWER; halving occupancy for f4-in-LDS (r8)
//     cost far more than the traffic it saved (latency-bound gathers need
//     all 32 waves/CU).
//
// Block = 4 points, 256 threads:
// Phase 0: 16 lanes compute per-(point,level) bilinear weights + 4 corner
//          pointers into LDS.
// Phase 1: flat (point, float4-channel-group) mapping; float4 gathers from
//          the 4 corners (16B-aligned), scalar LDS writes.  Phase-split from
//          stores (loads and stores never share a vmcnt window).
// Phase 2: block's 4x963-float chunk is contiguous and 16B-aligned in global
//          -> coalesced nontemporal float4 copy-out (no-allocate keeps the
//          1.5 MB feature maps resident in L2 under 385 MB of write data).

#define PTS  4
#define ROWF 963   // 3 coords + 960 samples
#define GPP  240   // float4 groups per point (960/4)

typedef float fx4 __attribute__((ext_vector_type(4)));

__global__ __launch_bounds__(256) void graphproj_kernel(
    const float* __restrict__ coords,
    const float* __restrict__ f1, const float* __restrict__ f2,
    const float* __restrict__ f3, const float* __restrict__ f4,
    float* __restrict__ out, int N)
{
    __shared__ __align__(16) float smem[PTS * ROWF];           // 15408 B
    __shared__ __align__(16) float s_w[PTS][4][4];             // w11,w21,w12,w22
    __shared__ const float* s_q[PTS][4][4];                    // corner ptrs

    const int b  = blockIdx.x;
    const int t  = threadIdx.x;
    const int p0 = b * PTS;
    const int npts = min(PTS, N - p0);

    // ---- phase 0: weights + corner pointers ----
    if (t < 4 * npts) {
        const int pt = t >> 2;
        const int lv = t & 3;
        const int p  = p0 + pt;
        const float X = coords[p * 3 + 0];
        const float Y = coords[p * 3 + 1];
        const float Z = coords[p * 3 + 2];
        float h = 250.0f * (-Y) / (-Z) + 112.0f;
        float w = 250.0f * X / (-Z) + 112.0f;
        h = fminf(fmaxf(h, 0.0f), 223.0f);
        w = fminf(fmaxf(w, 0.0f), 223.0f);

        const int   Hs[4] = {56, 28, 14, 7};
        const int   Cs[4] = {64, 128, 256, 512};
        const int   H = Hs[lv], C = Cs[lv];
        const float scale = (float)H / 224.0f;   // exact power-of-2 ratio
        const float x = h * scale, y = w * scale;
        const float x1f = floorf(x), x2f = fminf(ceilf(x), (float)(H - 1));
        const float y1f = floorf(y), y2f = fminf(ceilf(y), (float)(H - 1));
        const int xi1 = (int)x1f, xi2 = (int)x2f;
        const int yi1 = (int)y1f, yi2 = (int)y2f;

        s_w[pt][lv][0] = (x2f - x) * (y2f - y);   // w11 -> Q11 (xi1,yi1)
        s_w[pt][lv][1] = (x - x1f) * (y2f - y);   // w21 -> Q21 (xi2,yi1)
        s_w[pt][lv][2] = (x2f - x) * (y - y1f);   // w12 -> Q12 (xi1,yi2)
        s_w[pt][lv][3] = (x - x1f) * (y - y1f);   // w22 -> Q22 (xi2,yi2)

        const float* f = (lv == 0) ? f1 : (lv == 1) ? f2 : (lv == 2) ? f3 : f4;
        s_q[pt][lv][0] = f + (size_t)(xi1 * H + yi1) * C;
        s_q[pt][lv][1] = f + (size_t)(xi2 * H + yi1) * C;
        s_q[pt][lv][2] = f + (size_t)(xi1 * H + yi2) * C;
        s_q[pt][lv][3] = f + (size_t)(xi2 * H + yi2) * C;
    }
    // coords into the LDS chunk (cols 0..2 of each row)
    if (t >= 64 && t < 64 + 3 * npts) {
        const int i = t - 64;
        smem[(i / 3) * ROWF + (i % 3)] = coords[p0 * 3 + i];
    }
    __syncthreads();

    // ---- phase 1: gather + blend into LDS ----
    for (int gf = t; gf < npts * GPP; gf += 256) {
        const int pt = gf / GPP;
        const int g  = gf - pt * GPP;
        // level ranges: [0,16) L1, [16,48) L2, [48,112) L3, [112,240) L4
        const int lv = (g >= 16) + (g >= 48) + (g >= 112);
        const int c4 = g - ((lv == 0) ? 0 : (lv == 1) ? 16 : (lv == 2) ? 48 : 112);

        const float4 wv = *(const float4*)&s_w[pt][lv][0];
        const fx4* q11 = (const fx4*)s_q[pt][lv][0];
        const fx4* q21 = (const fx4*)s_q[pt][lv][1];
        const fx4* q12 = (const fx4*)s_q[pt][lv][2];
        const fx4* q22 = (const fx4*)s_q[pt][lv][3];

        const fx4 a  = q11[c4];
        const fx4 bb = q21[c4];
        const fx4 c  = q12[c4];
        const fx4 d  = q22[c4];

        float* o = &smem[pt * ROWF + 3 + 4 * g];
        o[0] = wv.x * a.x + wv.y * bb.x + wv.z * c.x + wv.w * d.x;
        o[1] = wv.x * a.y + wv.y * bb.y + wv.z * c.y + wv.w * d.y;
        o[2] = wv.x * a.z + wv.y * bb.z + wv.z * c.z + wv.w * d.z;
        o[3] = wv.x * a.w + wv.y * bb.w + wv.z * c.w + wv.w * d.w;
    }
    __syncthreads();

    // ---- phase 2: aligned coalesced copy-out ----
    if (npts == PTS) {
        const fx4* src = (const fx4*)smem;
        fx4* dst = (fx4*)(out + (size_t)p0 * ROWF);
        for (int i = t; i < PTS * ROWF / 4; i += 256) {   // 963 float4s
            __builtin_nontemporal_store(src[i], &dst[i]);
        }
    } else {
        for (int i = t; i < npts * ROWF; i += 256) {
            out[(size_t)p0 * ROWF + i] = smem[i];
        }
    }
}

extern "C" void kernel_launch(void* const* d_in, const int* in_sizes, int n_in,
                              void* d_out, int out_size, void* d_ws, size_t ws_size,
                              hipStream_t stream) {
    const float* coords = (const float*)d_in[0];
    const float* f1 = (const float*)d_in[1];
    const float* f2 = (const float*)d_in[2];
    const float* f3 = (const float*)d_in[3];
    const float* f4 = (const float*)d_in[4];
    float* out = (float*)d_out;
    const int N = in_sizes[0] / 3;

    const int blocks = (N + PTS - 1) / PTS;
    graphproj_kernel<<<blocks, 256, 0, stream>>>(coords, f1, f2, f3, f4, out, N);
}